// Round 1
// baseline (185.718 us; speedup 1.0000x reference)
//
#include <hip/hip_runtime.h>

// Ray termination probability scan along depth, depth-split 4 ways.
// voxels: [B=16, D=128, H=128, W=128] fp32, row-major (W contiguous).
// out[b, H-1-h, w] = sum_d o[b,d,h,w] * T_d,
//   o = clip(v, EPS, 1-EPS), T_d = prod_{k<d}(1-o_k), d=0 term carries exp(EPS).
//
// The scan is associative: per depth-chunk c compute (A_c, T_c); combine
//   A = A_0 + T_0 A_1 + T_0 T_1 A_2 + T_0 T_1 T_2 A_3.
// Chunks live in lane groups of one wave (lane = w4 + 16*chunk), combined with
// shuffles. This raises occupancy from 1 wave/SIMD to 4 waves/SIMD to hide
// HBM latency (previous version was latency-bound, not BW-bound).

#define EPS 1e-5f
#define EXP_EPS 1.0000100000500002f  // expf(1e-5f)

#define B_ 16
#define D_ 128
#define H_ 128
#define W_ 128
#define CH_ 4               // depth chunks per ray
#define CD_ (D_ / CH_)      // 32 depths per chunk

__device__ __forceinline__ float clampo(float v) {
    return fminf(fmaxf(v, EPS), 1.0f - EPS);
}

__global__ __launch_bounds__(256, 4) void ray_term_kernel(const float* __restrict__ vox,
                                                          float* __restrict__ out) {
    const int lane  = threadIdx.x;                   // 0..63, one wave per y-slice
    const int wv    = threadIdx.y;                   // 0..3
    const int chunk = lane >> 4;                     // 0..3 depth chunk
    const int w4    = (lane & 15) + 16 * (wv & 1);   // 0..31 -> w = 4*w4..4*w4+3
    const int h     = blockIdx.x * 2 + (wv >> 1);    // grid.x = H/2
    const int b     = blockIdx.y;

    // base points at [b, d = chunk*CD, h, 4*w4]
    const float4* __restrict__ src =
        (const float4*)(vox + (((size_t)b * D_ + (size_t)chunk * CD_) * H_ + h) * W_) + w4;
    const int dstride = H_ * W_ / 4;  // float4 stride between depth slices

    // First depth of the chunk peeled; only chunk 0's first term carries exp(EPS).
    const float s = (chunk == 0) ? EXP_EPS : 1.0f;
    float4 v0 = src[0];
    float o0 = clampo(v0.x), o1 = clampo(v0.y), o2 = clampo(v0.z), o3 = clampo(v0.w);
    float a0 = o0 * s, a1 = o1 * s, a2 = o2 * s, a3 = o3 * s;
    float t0 = 1.0f - o0, t1 = 1.0f - o1, t2 = 1.0f - o2, t3 = 1.0f - o3;

    #pragma unroll 8
    for (int d = 1; d < CD_; ++d) {
        float4 v = src[(size_t)d * dstride];
        o0 = clampo(v.x); o1 = clampo(v.y); o2 = clampo(v.z); o3 = clampo(v.w);
        a0 = fmaf(o0, t0, a0); t0 *= (1.0f - o0);
        a1 = fmaf(o1, t1, a1); t1 *= (1.0f - o1);
        a2 = fmaf(o2, t2, a2); t2 *= (1.0f - o2);
        a3 = fmaf(o3, t3, a3); t3 *= (1.0f - o3);
    }

    // Cross-chunk combine within the wave. Lanes {base, base+16, base+32, base+48}
    // hold chunks 0..3 of the same (h, w4).
    const int base = lane & 15;
    float u0, u1, u2, P;
#define COMBINE(T, A)                                  \
    u0 = __shfl((T), base + 0, 64);                    \
    u1 = __shfl((T), base + 16, 64);                   \
    u2 = __shfl((T), base + 32, 64);                   \
    P = 1.0f;                                          \
    if (chunk > 0) P = u0;                             \
    if (chunk > 1) P *= u1;                            \
    if (chunk > 2) P *= u2;                            \
    (A) *= P;                                          \
    (A) += __shfl_xor((A), 16, 64);                    \
    (A) += __shfl_xor((A), 32, 64);

    COMBINE(t0, a0)
    COMBINE(t1, a1)
    COMBINE(t2, a2)
    COMBINE(t3, a3)
#undef COMBINE

    // Lanes of chunk 0 write the result; vertical flip along H.
    if (chunk == 0) {
        float* __restrict__ dst =
            out + ((size_t)b * H_ + (size_t)(H_ - 1 - h)) * W_ + 4 * w4;
        *(float4*)dst = make_float4(a0, a1, a2, a3);
    }
}

extern "C" void kernel_launch(void* const* d_in, const int* in_sizes, int n_in,
                              void* d_out, int out_size, void* d_ws, size_t ws_size,
                              hipStream_t stream) {
    const float* vox = (const float*)d_in[0];
    float* out = (float*)d_out;
    dim3 block(64, 4, 1);            // 256 threads = 4 waves
    dim3 grid(H_ / 2, B_, 1);        // 64 x 16 = 1024 blocks -> 4 waves/SIMD
    ray_term_kernel<<<grid, block, 0, stream>>>(vox, out);
}

// Round 2
// 185.590 us; speedup vs baseline: 1.0007x; 1.0007x over previous
//
#include <hip/hip_runtime.h>

// Ray termination probability scan along depth.
// voxels: [B=16, D=128, H=128, W=128] fp32, row-major (W contiguous).
// out[b, H-1-h, w] = sum_d o[b,d,h,w] * T_d,
//   o = clip(v, EPS, 1-EPS), T_d = prod_{k<d}(1-o_k); d=0 term carries exp(EPS).
//
// v3: stream-efficiency version. 256 blocks (1 per CU) x 256 threads; each
// block reads a 4 KB fully-contiguous span (8 h-rows x W) per depth slice,
// walking D at 64 KB stride. Round-1 showed the kernel is NOT latency-bound
// (4x occupancy = no change), so this targets DRAM efficiency: fewer, wider
// streams (512 x 2KB -> 256 x 4KB per step), unroll 16 for 16 KB in
// flight/SIMD, and T-update as a single FMA.

#define EPS 1e-5f
#define EXP_EPS 1.0000100000500002f  // expf(1e-5f)

#define B_ 16
#define D_ 128
#define H_ 128
#define W_ 128

__device__ __forceinline__ float clampo(float v) {
    return fminf(fmaxf(v, EPS), 1.0f - EPS);
}

__global__ __launch_bounds__(256, 1) void ray_term_kernel(const float* __restrict__ vox,
                                                          float* __restrict__ out) {
    const int tid = threadIdx.x;   // 0..255
    const int hg  = blockIdx.x;    // 0..15 : group of 8 consecutive h-rows
    const int b   = blockIdx.y;

    // Per depth slice, block footprint = rows [8*hg, 8*hg+8) x all W = 4 KB
    // contiguous; thread tid's float4 sits at slice_base + hg*256 + tid.
    const int dstride = H_ * W_ / 4;  // 4096 float4 per depth slice
    const float4* __restrict__ src =
        (const float4*)vox + (size_t)b * D_ * dstride + hg * (8 * W_ / 4) + tid;

    // d = 0 peeled: carries the exp(EPS) factor from the eps slab.
    float4 v0 = src[0];
    float o0 = clampo(v0.x), o1 = clampo(v0.y), o2 = clampo(v0.z), o3 = clampo(v0.w);
    float a0 = o0 * EXP_EPS, a1 = o1 * EXP_EPS, a2 = o2 * EXP_EPS, a3 = o3 * EXP_EPS;
    float t0 = 1.0f - o0, t1 = 1.0f - o1, t2 = 1.0f - o2, t3 = 1.0f - o3;

    #pragma unroll 16
    for (int d = 1; d < D_; ++d) {
        float4 v = src[(size_t)d * dstride];
        o0 = clampo(v.x); o1 = clampo(v.y); o2 = clampo(v.z); o3 = clampo(v.w);
        a0 = fmaf(o0, t0, a0); t0 = fmaf(-o0, t0, t0);
        a1 = fmaf(o1, t1, a1); t1 = fmaf(-o1, t1, t1);
        a2 = fmaf(o2, t2, a2); t2 = fmaf(-o2, t2, t2);
        a3 = fmaf(o3, t3, a3); t3 = fmaf(-o3, t3, t3);
    }

    // vertical flip along H on output
    const int h = hg * 8 + (tid >> 5);
    float* __restrict__ dst =
        out + ((size_t)b * H_ + (size_t)(H_ - 1 - h)) * W_ + 4 * (tid & 31);
    *(float4*)dst = make_float4(a0, a1, a2, a3);
}

extern "C" void kernel_launch(void* const* d_in, const int* in_sizes, int n_in,
                              void* d_out, int out_size, void* d_ws, size_t ws_size,
                              hipStream_t stream) {
    const float* vox = (const float*)d_in[0];
    float* out = (float*)d_out;
    dim3 block(256, 1, 1);        // 4 waves
    dim3 grid(H_ / 8, B_, 1);     // 16 x 16 = 256 blocks = 1 per CU
    ray_term_kernel<<<grid, block, 0, stream>>>(vox, out);
}